// Round 4
// baseline (232.721 us; speedup 1.0000x reference)
//
#include <hip/hip_runtime.h>
#include <math.h>

#define NREL  32
#define NENT  2048
#define NATTR 8
#define WIDTH 256
#define NK    (2 * NREL + NATTR)   // 72
#define CHUNKS 64
#define ROWS  (NENT / CHUNKS)      // 32 rows per block

// ---------------------------------------------------------------------------
// Kernel A: one pass over database. Block = (relation r, 32-row chunk).
// Wave w owns 8 FULL rows (16 independent float4 loads in flight per pair of
// rows). NO cross-lane ops in the hot loop: per-row lane partials go to a
// transposed LDS array rpart[64][33] (2-way bank aliasing = free), finished
// once per block. Column partials acc[8] combined across waves via a 32KB
// LDS buffer overlaid on rpart (3-phase sync). LDS = 32KB -> 4 blocks/CU;
// launch_bounds pins VGPR<=128 -> 16 waves/CU.
// ---------------------------------------------------------------------------
__global__ __launch_bounds__(256, 4) void reduce_db_kernel(
    const float* __restrict__ db,
    float* __restrict__ qout,        // quantified region [72][2048]
    float* __restrict__ partial)     // [NREL*CHUNKS][2048]
{
    const int bx    = blockIdx.x;
    const int r     = bx >> 6;             // / CHUNKS
    const int chunk = bx & (CHUNKS - 1);
    const int tid   = threadIdx.x;
    const int wave  = tid >> 6;
    const int lane  = tid & 63;
    const int i0    = chunk * ROWS;

    __shared__ __align__(16) float smem[4][NENT];        // 32KB, dual-purpose
    float (*rpart)[33] = reinterpret_cast<float(*)[33]>(&smem[0][0]); // [64][33]

    // wave w owns rows i0 + w*8 .. +7, full 2048 columns
    const float4* base = reinterpret_cast<const float4*>(db)
                       + (size_t)r * NENT * (NENT / 4)
                       + (size_t)(i0 + wave * 8) * (NENT / 4)
                       + lane;

    float4 acc[8];
#pragma unroll
    for (int k = 0; k < 8; ++k) acc[k] = make_float4(0.f, 0.f, 0.f, 0.f);

#pragma unroll
    for (int j = 0; j < 8; j += 2) {
        const float4* rowA = base + (size_t)j * (NENT / 4);
        const float4* rowB = rowA + (NENT / 4);
        float rsA = 0.f, rsB = 0.f;
        // 16 independent float4 loads, no cross-lane ops anywhere in the loop
#pragma unroll
        for (int k = 0; k < 8; ++k) {
            float4 v = rowA[k * 64];
            acc[k].x += v.x; acc[k].y += v.y;
            acc[k].z += v.z; acc[k].w += v.w;
            rsA += (v.x + v.y) + (v.z + v.w);
        }
#pragma unroll
        for (int k = 0; k < 8; ++k) {
            float4 v = rowB[k * 64];
            acc[k].x += v.x; acc[k].y += v.y;
            acc[k].z += v.z; acc[k].w += v.w;
            rsB += (v.x + v.y) + (v.z + v.w);
        }
        // fire-and-forget per-lane row partials (transposed, 2-way banks)
        rpart[lane][wave * 8 + j]     = rsA;
        rpart[lane][wave * 8 + j + 1] = rsB;
    }
    __syncthreads();

    // phase 2: finish row sums. thread t: row = t>>3, 8-lane segment t&7.
    {
        const int row = tid >> 3;
        const int seg = tid & 7;
        float s = 0.f;
#pragma unroll
        for (int i = 0; i < 8; ++i) s += rpart[seg * 8 + i][row];
        s += __shfl_xor(s, 1, 64);
        s += __shfl_xor(s, 2, 64);
        s += __shfl_xor(s, 4, 64);
        if (seg == 0)
            qout[(size_t)(NREL + r) * NENT + i0 + row] = 1.f - __expf(-s);
    }
    __syncthreads();

    // phase 3: combine the 4 waves' column partials (overlay rpart space)
#pragma unroll
    for (int k = 0; k < 8; ++k)
        *reinterpret_cast<float4*>(&smem[wave][k * 256 + lane * 4]) = acc[k];
    __syncthreads();

    float4* part4 = reinterpret_cast<float4*>(partial) + (size_t)bx * (NENT / 4);
    for (int g = tid; g < NENT / 4; g += 256) {
        float4 a0 = *reinterpret_cast<const float4*>(&smem[0][g * 4]);
        float4 a1 = *reinterpret_cast<const float4*>(&smem[1][g * 4]);
        float4 a2 = *reinterpret_cast<const float4*>(&smem[2][g * 4]);
        float4 a3 = *reinterpret_cast<const float4*>(&smem[3][g * 4]);
        float4 s;
        s.x = (a0.x + a1.x) + (a2.x + a3.x);
        s.y = (a0.y + a1.y) + (a2.y + a3.y);
        s.z = (a0.z + a1.z) + (a2.z + a3.z);
        s.w = (a0.w + a1.w) + (a2.w + a3.w);
        part4[g] = s;
    }
}

// ---------------------------------------------------------------------------
// Kernel B (merged): blocks 0..319 finalize column sums (fully-unrolled
// 64 independent chunk loads) + attribute rows; block 320 does the weights
// softmax with fully-unrolled independent loads.
// ---------------------------------------------------------------------------
#define FIN_BLOCKS ((NREL + NATTR) * NENT / 256)   // 320

__global__ __launch_bounds__(256) void finalize_softmax_kernel(
    const float* __restrict__ partial,
    const float* __restrict__ attrs,
    const float* __restrict__ W,
    float* __restrict__ qout,
    float* __restrict__ sw)
{
    const int b = blockIdx.x;
    if (b < FIN_BLOCKS) {
        const int idx = b * 256 + threadIdx.x;   // over (32+8)*2048
        const int row = idx >> 11;
        const int n   = idx & (NENT - 1);
        if (row < NREL) {
            float s = 0.f;
#pragma unroll
            for (int c = 0; c < CHUNKS; ++c)     // compile-time: 64 indep loads
                s += partial[((size_t)(row * CHUNKS + c) << 11) + n];
            qout[((size_t)row << 11) + n] = 1.f - __expf(-s);
        } else {
            const int a = row - NREL;
            float v = attrs[((size_t)a << 11) + n];
            qout[((size_t)(2 * NREL + a) << 11) + n] = 1.f - __expf(-2.f * v);
        }
    } else {
        // softmax over the 72 rows of weights, per output column w
        const int w = threadIdx.x;  // 0..255
        float v[NK];
#pragma unroll
        for (int k = 0; k < NK; ++k) v[k] = W[k * WIDTH + w];  // 72 indep loads
        float m = v[0];
#pragma unroll
        for (int k = 1; k < NK; ++k) m = fmaxf(m, v[k]);
        float s = 0.f;
#pragma unroll
        for (int k = 0; k < NK; ++k) { v[k] = __expf(v[k] - m); s += v[k]; }
        const float inv = 1.f / s;
#pragma unroll
        for (int k = 0; k < NK; ++k) sw[k * WIDTH + w] = v[k] * inv;
    }
}

// ---------------------------------------------------------------------------
// Kernel C: outputs[w][n] = sum_k sw[k][w] * quantified[k][n].
// 2 blocks per w (512 blocks); sw column staged in LDS (broadcast reads);
// 1 float4 per thread; quant is L2-resident.
// ---------------------------------------------------------------------------
__global__ __launch_bounds__(256) void matmul_kernel(
    const float* __restrict__ sw,
    const float* __restrict__ quant,
    float* __restrict__ out)
{
    const int w = blockIdx.x >> 1;                           // 0..255
    const int g = (blockIdx.x & 1) * 256 + threadIdx.x;      // float4 col

    __shared__ float sWcol[NK];
    if (threadIdx.x < NK) sWcol[threadIdx.x] = sw[threadIdx.x * WIDTH + w];
    __syncthreads();

    const float4* q4 = reinterpret_cast<const float4*>(quant);
    float4 a = make_float4(0.f, 0.f, 0.f, 0.f);
#pragma unroll 8
    for (int k = 0; k < NK; ++k) {
        const float s = sWcol[k];
        float4 v = q4[k * (NENT / 4) + g];
        a.x += s * v.x; a.y += s * v.y; a.z += s * v.z; a.w += s * v.w;
    }
    reinterpret_cast<float4*>(out)[(size_t)w * (NENT / 4) + g] = a;
}

extern "C" void kernel_launch(void* const* d_in, const int* in_sizes, int n_in,
                              void* d_out, int out_size, void* d_ws, size_t ws_size,
                              hipStream_t stream)
{
    const float* db    = (const float*)d_in[0];  // [32][2048][2048]
    const float* attrs = (const float*)d_in[1];  // [8][2048]
    const float* W     = (const float*)d_in[2];  // [72][256]

    float* out   = (float*)d_out;                    // [256][2048]
    float* quant = out + (size_t)WIDTH * NENT;       // [72][2048]

    float* partial = (float*)d_ws;                             // [32*64][2048]
    float* sw      = partial + (size_t)NREL * CHUNKS * NENT;   // [72][256]

    reduce_db_kernel<<<NREL * CHUNKS, 256, 0, stream>>>(db, quant, partial);
    finalize_softmax_kernel<<<FIN_BLOCKS + 1, 256, 0, stream>>>(
        partial, attrs, W, quant, sw);
    matmul_kernel<<<WIDTH * 2, 256, 0, stream>>>(sw, quant, out);
}

// Round 5
// 125.805 us; speedup vs baseline: 1.8499x; 1.8499x over previous
//
#include <hip/hip_runtime.h>
#include <math.h>

#define NREL  32
#define NENT  2048
#define NATTR 8
#define WIDTH 256
#define NK    (2 * NREL + NATTR)   // 72
#define CHUNKS 64
#define ROWS  (NENT / CHUNKS)      // 32 rows per block

// ---------------------------------------------------------------------------
// Kernel A: one pass over database. Block = (relation r, 32-row chunk).
// Identical streaming structure to the 124.9us R2 kernel (wave owns 8 full
// rows, 16 independent float4 loads in flight per row-pair, acc[8] column
// partials). ONE change: the in-loop 7-op dependent shuffle chain is replaced
// by 2 fire-and-forget transposed LDS stores (rpart[lane][row], stride 33 =
// 2-way bank aliasing = free); row sums finished once per block in phase 2.
// Row loop bound is a RUNTIME arg so the compiler cannot unroll it (keeps
// VGPR ~110, no spills — the R4 mistake). No launch_bounds cap.
// ---------------------------------------------------------------------------
__global__ __launch_bounds__(256) void reduce_db_kernel(
    const float* __restrict__ db,
    float* __restrict__ qout,        // quantified region [72][2048]
    float* __restrict__ partial,     // [NREL*CHUNKS][2048]
    int rowsPerWave)                 // = 8 (runtime to forbid unrolling)
{
    const int bx    = blockIdx.x;
    const int r     = bx >> 6;             // / CHUNKS
    const int chunk = bx & (CHUNKS - 1);
    const int tid   = threadIdx.x;
    const int wave  = tid >> 6;
    const int lane  = tid & 63;
    const int i0    = chunk * ROWS;
    const int rowBase = wave * rowsPerWave;      // wave's first row in block

    __shared__ __align__(16) float smem[4][NENT];        // 32KB, dual-purpose
    float (*rpart)[33] = reinterpret_cast<float(*)[33]>(&smem[0][0]); // [64][33]

    const float4* base = reinterpret_cast<const float4*>(db)
                       + (size_t)r * NENT * (NENT / 4)
                       + (size_t)(i0 + rowBase) * (NENT / 4)
                       + lane;

    float4 acc[8];
#pragma unroll
    for (int k = 0; k < 8; ++k) acc[k] = make_float4(0.f, 0.f, 0.f, 0.f);

    for (int j = 0; j < rowsPerWave; j += 2) {
        const float4* rowA = base + (size_t)j * (NENT / 4);
        const float4* rowB = rowA + (NENT / 4);
        float rsA = 0.f, rsB = 0.f;
        // 16 independent float4 loads; NO cross-lane ops in the loop
#pragma unroll
        for (int k = 0; k < 8; ++k) {
            float4 v = rowA[k * 64];
            acc[k].x += v.x; acc[k].y += v.y;
            acc[k].z += v.z; acc[k].w += v.w;
            rsA += (v.x + v.y) + (v.z + v.w);
        }
#pragma unroll
        for (int k = 0; k < 8; ++k) {
            float4 v = rowB[k * 64];
            acc[k].x += v.x; acc[k].y += v.y;
            acc[k].z += v.z; acc[k].w += v.w;
            rsB += (v.x + v.y) + (v.z + v.w);
        }
        // fire-and-forget per-lane row partials (transposed, 2-way banks)
        rpart[lane][rowBase + j]     = rsA;
        rpart[lane][rowBase + j + 1] = rsB;
    }
    __syncthreads();

    // phase 2: finish row sums. thread t: row = t>>3, 8-lane segment t&7.
    {
        const int row = tid >> 3;       // 0..31
        const int seg = tid & 7;
        float s = 0.f;
#pragma unroll
        for (int i = 0; i < 8; ++i) s += rpart[seg * 8 + i][row];
        s += __shfl_xor(s, 1, 64);
        s += __shfl_xor(s, 2, 64);
        s += __shfl_xor(s, 4, 64);
        if (seg == 0)
            qout[(size_t)(NREL + r) * NENT + i0 + row] = 1.f - __expf(-s);
    }
    __syncthreads();

    // phase 3: combine the 4 waves' column partials (overlay rpart space)
#pragma unroll
    for (int k = 0; k < 8; ++k)
        *reinterpret_cast<float4*>(&smem[wave][k * 256 + lane * 4]) = acc[k];
    __syncthreads();

    float4* part4 = reinterpret_cast<float4*>(partial) + (size_t)bx * (NENT / 4);
    for (int g = tid; g < NENT / 4; g += 256) {
        float4 a0 = *reinterpret_cast<const float4*>(&smem[0][g * 4]);
        float4 a1 = *reinterpret_cast<const float4*>(&smem[1][g * 4]);
        float4 a2 = *reinterpret_cast<const float4*>(&smem[2][g * 4]);
        float4 a3 = *reinterpret_cast<const float4*>(&smem[3][g * 4]);
        float4 s;
        s.x = (a0.x + a1.x) + (a2.x + a3.x);
        s.y = (a0.y + a1.y) + (a2.y + a3.y);
        s.z = (a0.z + a1.z) + (a2.z + a3.z);
        s.w = (a0.w + a1.w) + (a2.w + a3.w);
        part4[g] = s;
    }
}

// ---------------------------------------------------------------------------
// Kernel B (merged): blocks 0..319 finalize column sums (fully-unrolled
// 64 independent chunk loads) + attribute rows; block 320 does the weights
// softmax with fully-unrolled independent loads.
// ---------------------------------------------------------------------------
#define FIN_BLOCKS ((NREL + NATTR) * NENT / 256)   // 320

__global__ __launch_bounds__(256) void finalize_softmax_kernel(
    const float* __restrict__ partial,
    const float* __restrict__ attrs,
    const float* __restrict__ W,
    float* __restrict__ qout,
    float* __restrict__ sw)
{
    const int b = blockIdx.x;
    if (b < FIN_BLOCKS) {
        const int idx = b * 256 + threadIdx.x;   // over (32+8)*2048
        const int row = idx >> 11;
        const int n   = idx & (NENT - 1);
        if (row < NREL) {
            float s = 0.f;
#pragma unroll
            for (int c = 0; c < CHUNKS; ++c)     // compile-time: 64 indep loads
                s += partial[((size_t)(row * CHUNKS + c) << 11) + n];
            qout[((size_t)row << 11) + n] = 1.f - __expf(-s);
        } else {
            const int a = row - NREL;
            float v = attrs[((size_t)a << 11) + n];
            qout[((size_t)(2 * NREL + a) << 11) + n] = 1.f - __expf(-2.f * v);
        }
    } else {
        // softmax over the 72 rows of weights, per output column w
        const int w = threadIdx.x;  // 0..255
        float v[NK];
#pragma unroll
        for (int k = 0; k < NK; ++k) v[k] = W[k * WIDTH + w];  // 72 indep loads
        float m = v[0];
#pragma unroll
        for (int k = 1; k < NK; ++k) m = fmaxf(m, v[k]);
        float s = 0.f;
#pragma unroll
        for (int k = 0; k < NK; ++k) { v[k] = __expf(v[k] - m); s += v[k]; }
        const float inv = 1.f / s;
#pragma unroll
        for (int k = 0; k < NK; ++k) sw[k * WIDTH + w] = v[k] * inv;
    }
}

// ---------------------------------------------------------------------------
// Kernel C: outputs[w][n] = sum_k sw[k][w] * quantified[k][n].
// 2 blocks per w (512 blocks); sw column staged in LDS (broadcast reads);
// 1 float4 per thread; quant is L2-resident.
// ---------------------------------------------------------------------------
__global__ __launch_bounds__(256) void matmul_kernel(
    const float* __restrict__ sw,
    const float* __restrict__ quant,
    float* __restrict__ out)
{
    const int w = blockIdx.x >> 1;                           // 0..255
    const int g = (blockIdx.x & 1) * 256 + threadIdx.x;      // float4 col

    __shared__ float sWcol[NK];
    if (threadIdx.x < NK) sWcol[threadIdx.x] = sw[threadIdx.x * WIDTH + w];
    __syncthreads();

    const float4* q4 = reinterpret_cast<const float4*>(quant);
    float4 a = make_float4(0.f, 0.f, 0.f, 0.f);
#pragma unroll 8
    for (int k = 0; k < NK; ++k) {
        const float s = sWcol[k];
        float4 v = q4[k * (NENT / 4) + g];
        a.x += s * v.x; a.y += s * v.y; a.z += s * v.z; a.w += s * v.w;
    }
    reinterpret_cast<float4*>(out)[(size_t)w * (NENT / 4) + g] = a;
}

extern "C" void kernel_launch(void* const* d_in, const int* in_sizes, int n_in,
                              void* d_out, int out_size, void* d_ws, size_t ws_size,
                              hipStream_t stream)
{
    const float* db    = (const float*)d_in[0];  // [32][2048][2048]
    const float* attrs = (const float*)d_in[1];  // [8][2048]
    const float* W     = (const float*)d_in[2];  // [72][256]

    float* out   = (float*)d_out;                    // [256][2048]
    float* quant = out + (size_t)WIDTH * NENT;       // [72][2048]

    float* partial = (float*)d_ws;                             // [32*64][2048]
    float* sw      = partial + (size_t)NREL * CHUNKS * NENT;   // [72][256]

    reduce_db_kernel<<<NREL * CHUNKS, 256, 0, stream>>>(db, quant, partial,
                                                        ROWS / 4);
    finalize_softmax_kernel<<<FIN_BLOCKS + 1, 256, 0, stream>>>(
        partial, attrs, W, quant, sw);
    matmul_kernel<<<WIDTH * 2, 256, 0, stream>>>(sw, quant, out);
}

// Round 6
// 117.085 us; speedup vs baseline: 1.9876x; 1.0745x over previous
//
#include <hip/hip_runtime.h>
#include <math.h>

#define NREL  32
#define NENT  2048
#define NATTR 8
#define WIDTH 256
#define NK    (2 * NREL + NATTR)   // 72
#define CHUNKS_OUT 16              // partial rows per relation
#define SUBS  4                    // sub-chunks (32 rows) per block

// ---------------------------------------------------------------------------
// Kernel A: one pass over database. Block = (relation r, 128-row chunk),
// processed as 4 serial 32-row sub-chunks. Streaming inner loop is IDENTICAL
// to the 124.9us R2/R5 kernel (wave owns 8 full rows, 16 independent float4
// loads in flight, acc[8] column partials in registers across ALL 128 rows).
// Row sums via fire-and-forget transposed LDS (2-way banks, free), finished
// per sub-chunk. One block epilogue combines acc -> partial[bx] (512 rows
// total = 8MB round-trip vs 33MB before). Runtime loop bounds forbid
// over-unrolling (VGPR stays ~110).
// ---------------------------------------------------------------------------
__global__ __launch_bounds__(256) void reduce_db_kernel(
    const float* __restrict__ db,
    float* __restrict__ qout,        // quantified region [72][2048]
    float* __restrict__ partial,     // [NREL*CHUNKS_OUT][2048]
    int rowsPerWave,                 // = 8  (runtime)
    int nSubs)                       // = 4  (runtime)
{
    const int bx   = blockIdx.x;
    const int r    = bx >> 4;              // / CHUNKS_OUT
    const int cOut = bx & (CHUNKS_OUT - 1);
    const int tid  = threadIdx.x;
    const int wave = tid >> 6;
    const int lane = tid & 63;

    __shared__ __align__(16) float smem[4][NENT];        // 32KB, dual-purpose
    float (*rpart)[33] = reinterpret_cast<float(*)[33]>(&smem[0][0]); // [64][33]

    const size_t rowStride = NENT / 4;
    const float4* relBase = reinterpret_cast<const float4*>(db)
                          + (size_t)r * NENT * rowStride
                          + (size_t)(cOut * 128) * rowStride
                          + lane;

    float4 acc[8];
#pragma unroll
    for (int k = 0; k < 8; ++k) acc[k] = make_float4(0.f, 0.f, 0.f, 0.f);

    for (int sc = 0; sc < nSubs; ++sc) {
        const int i0 = sc * 32;                  // local row base
        const float4* base = relBase
                           + (size_t)(i0 + wave * rowsPerWave) * rowStride;

        for (int j = 0; j < rowsPerWave; j += 2) {
            const float4* rowA = base + (size_t)j * rowStride;
            const float4* rowB = rowA + rowStride;
            float rsA = 0.f, rsB = 0.f;
            // 16 independent float4 loads; NO cross-lane ops in the loop
#pragma unroll
            for (int k = 0; k < 8; ++k) {
                float4 v = rowA[k * 64];
                acc[k].x += v.x; acc[k].y += v.y;
                acc[k].z += v.z; acc[k].w += v.w;
                rsA += (v.x + v.y) + (v.z + v.w);
            }
#pragma unroll
            for (int k = 0; k < 8; ++k) {
                float4 v = rowB[k * 64];
                acc[k].x += v.x; acc[k].y += v.y;
                acc[k].z += v.z; acc[k].w += v.w;
                rsB += (v.x + v.y) + (v.z + v.w);
            }
            rpart[lane][wave * rowsPerWave + j]     = rsA;
            rpart[lane][wave * rowsPerWave + j + 1] = rsB;
        }
        __syncthreads();

        // finish row sums for this sub-chunk: thread t -> (row, 8-lane seg)
        {
            const int row = tid >> 3;       // 0..31 (local)
            const int seg = tid & 7;
            float t = 0.f;
#pragma unroll
            for (int i = 0; i < 8; ++i) t += rpart[seg * 8 + i][row];
            t += __shfl_xor(t, 1, 64);
            t += __shfl_xor(t, 2, 64);
            t += __shfl_xor(t, 4, 64);
            if (seg == 0)
                qout[(size_t)(NREL + r) * NENT + cOut * 128 + i0 + row] =
                    1.f - __expf(-t);
        }
        __syncthreads();   // rpart reads done before next sub-chunk rewrites
    }

    // block epilogue: combine the 4 waves' column partials (overlay rpart)
#pragma unroll
    for (int k = 0; k < 8; ++k)
        *reinterpret_cast<float4*>(&smem[wave][k * 256 + lane * 4]) = acc[k];
    __syncthreads();

    float4* part4 = reinterpret_cast<float4*>(partial) + (size_t)bx * rowStride;
    for (int g = tid; g < NENT / 4; g += 256) {
        float4 a0 = *reinterpret_cast<const float4*>(&smem[0][g * 4]);
        float4 a1 = *reinterpret_cast<const float4*>(&smem[1][g * 4]);
        float4 a2 = *reinterpret_cast<const float4*>(&smem[2][g * 4]);
        float4 a3 = *reinterpret_cast<const float4*>(&smem[3][g * 4]);
        float4 s;
        s.x = (a0.x + a1.x) + (a2.x + a3.x);
        s.y = (a0.y + a1.y) + (a2.y + a3.y);
        s.z = (a0.z + a1.z) + (a2.z + a3.z);
        s.w = (a0.w + a1.w) + (a2.w + a3.w);
        part4[g] = s;
    }
}

// ---------------------------------------------------------------------------
// Kernel B (merged): blocks 0..319 finalize column sums (16 fully-unrolled
// independent chunk loads) + attribute rows; block 320 does the weights
// softmax with fully-unrolled independent loads.
// ---------------------------------------------------------------------------
#define FIN_BLOCKS ((NREL + NATTR) * NENT / 256)   // 320

__global__ __launch_bounds__(256) void finalize_softmax_kernel(
    const float* __restrict__ partial,
    const float* __restrict__ attrs,
    const float* __restrict__ W,
    float* __restrict__ qout,
    float* __restrict__ sw)
{
    const int b = blockIdx.x;
    if (b < FIN_BLOCKS) {
        const int idx = b * 256 + threadIdx.x;   // over (32+8)*2048
        const int row = idx >> 11;
        const int n   = idx & (NENT - 1);
        if (row < NREL) {
            float s = 0.f;
#pragma unroll
            for (int c = 0; c < CHUNKS_OUT; ++c) // 16 independent loads
                s += partial[((size_t)(row * CHUNKS_OUT + c) << 11) + n];
            qout[((size_t)row << 11) + n] = 1.f - __expf(-s);
        } else {
            const int a = row - NREL;
            float v = attrs[((size_t)a << 11) + n];
            qout[((size_t)(2 * NREL + a) << 11) + n] = 1.f - __expf(-2.f * v);
        }
    } else {
        // softmax over the 72 rows of weights, per output column w
        const int w = threadIdx.x;  // 0..255
        float v[NK];
#pragma unroll
        for (int k = 0; k < NK; ++k) v[k] = W[k * WIDTH + w];  // 72 indep loads
        float m = v[0];
#pragma unroll
        for (int k = 1; k < NK; ++k) m = fmaxf(m, v[k]);
        float s = 0.f;
#pragma unroll
        for (int k = 0; k < NK; ++k) { v[k] = __expf(v[k] - m); s += v[k]; }
        const float inv = 1.f / s;
#pragma unroll
        for (int k = 0; k < NK; ++k) sw[k * WIDTH + w] = v[k] * inv;
    }
}

// ---------------------------------------------------------------------------
// Kernel C: outputs[w][n] = sum_k sw[k][w] * quantified[k][n], tiled.
// Block = (32 w's) x (128 cols): quant tile [72][128] (36KB) + sw tile
// [72][32] (9KB) staged in LDS ONCE -> total tile reads 5.8MB (vs 147MB of
// redundant L2/L3 reads before). 128 blocks; thread = (wl, colgrp of 16).
// ---------------------------------------------------------------------------
#define CW   32
#define CCOL 128

__global__ __launch_bounds__(256) void matmul_kernel(
    const float* __restrict__ sw,
    const float* __restrict__ quant,
    float* __restrict__ out)
{
    __shared__ float qt[NK][CCOL];    // 36KB
    __shared__ float swt[NK][CW];     // 9KB
    const int wg  = blockIdx.x >> 4;       // 0..7
    const int cg  = blockIdx.x & 15;       // 0..15
    const int w0  = wg * CW;
    const int c0  = cg * CCOL;
    const int tid = threadIdx.x;

    const float4* q4 = reinterpret_cast<const float4*>(quant);
#pragma unroll
    for (int i = tid; i < NK * (CCOL / 4); i += 256) {   // 9 iters
        const int k = i >> 5;        // CCOL/4 = 32 float4 per row
        const int c = i & 31;
        *reinterpret_cast<float4*>(&qt[k][c * 4]) =
            q4[(size_t)k * (NENT / 4) + (c0 >> 2) + c];
    }
#pragma unroll
    for (int i = tid; i < NK * CW; i += 256) {           // 9 iters
        const int k  = i >> 5;       // CW = 32
        const int wl = i & 31;
        swt[k][wl] = sw[k * WIDTH + w0 + wl];
    }
    __syncthreads();

    const int wl = tid >> 3;          // 0..31
    const int cl = (tid & 7) * 16;    // col offset, 16 cols/thread
    float4 a0 = make_float4(0.f, 0.f, 0.f, 0.f);
    float4 a1 = a0, a2 = a0, a3 = a0;
#pragma unroll 8
    for (int k = 0; k < NK; ++k) {
        const float s = swt[k][wl];
        const float4* row = reinterpret_cast<const float4*>(&qt[k][cl]);
        float4 v0 = row[0], v1 = row[1], v2 = row[2], v3 = row[3];
        a0.x += s * v0.x; a0.y += s * v0.y; a0.z += s * v0.z; a0.w += s * v0.w;
        a1.x += s * v1.x; a1.y += s * v1.y; a1.z += s * v1.z; a1.w += s * v1.w;
        a2.x += s * v2.x; a2.y += s * v2.y; a2.z += s * v2.z; a2.w += s * v2.w;
        a3.x += s * v3.x; a3.y += s * v3.y; a3.z += s * v3.z; a3.w += s * v3.w;
    }
    float4* o4 = reinterpret_cast<float4*>(out + (size_t)(w0 + wl) * NENT + c0 + cl);
    o4[0] = a0; o4[1] = a1; o4[2] = a2; o4[3] = a3;
}

extern "C" void kernel_launch(void* const* d_in, const int* in_sizes, int n_in,
                              void* d_out, int out_size, void* d_ws, size_t ws_size,
                              hipStream_t stream)
{
    const float* db    = (const float*)d_in[0];  // [32][2048][2048]
    const float* attrs = (const float*)d_in[1];  // [8][2048]
    const float* W     = (const float*)d_in[2];  // [72][256]

    float* out   = (float*)d_out;                    // [256][2048]
    float* quant = out + (size_t)WIDTH * NENT;       // [72][2048]

    float* partial = (float*)d_ws;                               // [512][2048]
    float* sw      = partial + (size_t)NREL * CHUNKS_OUT * NENT; // [72][256]

    reduce_db_kernel<<<NREL * CHUNKS_OUT, 256, 0, stream>>>(
        db, quant, partial, 8, SUBS);
    finalize_softmax_kernel<<<FIN_BLOCKS + 1, 256, 0, stream>>>(
        partial, attrs, W, quant, sw);
    matmul_kernel<<<(WIDTH / CW) * (NENT / CCOL), 256, 0, stream>>>(
        sw, quant, out);
}

// Round 7
// 100.225 us; speedup vs baseline: 2.3220x; 1.1682x over previous
//
#include <hip/hip_runtime.h>
#include <math.h>

#define NREL  32
#define NENT  2048
#define NATTR 8
#define WIDTH 256
#define NK    (2 * NREL + NATTR)   // 72
#define CHUNKS_OUT 16              // partial rows per relation
#define SUBS  4                    // sub-chunks (32 rows) per block

typedef float f4 __attribute__((ext_vector_type(4)));

// ---------------------------------------------------------------------------
// Kernel A: one pass over database. Block = (relation r, 128-row chunk),
// processed as 4 serial 32-row sub-chunks. Identical structure to the
// 117.1us R6 kernel; ONE change: db reads are NON-TEMPORAL (db is a 512MB
// zero-reuse stream -> avoid L2/L3 allocation pressure). Row sums via
// fire-and-forget transposed LDS (2-way banks, free). acc[8] column partials
// in registers across all 128 rows; one epilogue -> partial[bx].
// ---------------------------------------------------------------------------
__global__ __launch_bounds__(256) void reduce_db_kernel(
    const float* __restrict__ db,
    float* __restrict__ qout,        // quantified region [72][2048]
    float* __restrict__ partial,     // [NREL*CHUNKS_OUT][2048]
    int rowsPerWave,                 // = 8  (runtime)
    int nSubs)                       // = 4  (runtime)
{
    const int bx   = blockIdx.x;
    const int r    = bx >> 4;              // / CHUNKS_OUT
    const int cOut = bx & (CHUNKS_OUT - 1);
    const int tid  = threadIdx.x;
    const int wave = tid >> 6;
    const int lane = tid & 63;

    __shared__ __align__(16) float smem[4][NENT];        // 32KB, dual-purpose
    float (*rpart)[33] = reinterpret_cast<float(*)[33]>(&smem[0][0]); // [64][33]

    const size_t rowStride = NENT / 4;
    const f4* relBase = reinterpret_cast<const f4*>(db)
                      + (size_t)r * NENT * rowStride
                      + (size_t)(cOut * 128) * rowStride
                      + lane;

    f4 acc[8];
#pragma unroll
    for (int k = 0; k < 8; ++k) acc[k] = (f4)0.f;

    for (int sc = 0; sc < nSubs; ++sc) {
        const int i0 = sc * 32;                  // local row base
        const f4* base = relBase
                       + (size_t)(i0 + wave * rowsPerWave) * rowStride;

        for (int j = 0; j < rowsPerWave; j += 2) {
            const f4* rowA = base + (size_t)j * rowStride;
            const f4* rowB = rowA + rowStride;
            float rsA = 0.f, rsB = 0.f;
            // 16 independent NON-TEMPORAL float4 loads; no cross-lane ops
#pragma unroll
            for (int k = 0; k < 8; ++k) {
                f4 v = __builtin_nontemporal_load(rowA + k * 64);
                acc[k] += v;
                rsA += (v.x + v.y) + (v.z + v.w);
            }
#pragma unroll
            for (int k = 0; k < 8; ++k) {
                f4 v = __builtin_nontemporal_load(rowB + k * 64);
                acc[k] += v;
                rsB += (v.x + v.y) + (v.z + v.w);
            }
            rpart[lane][wave * rowsPerWave + j]     = rsA;
            rpart[lane][wave * rowsPerWave + j + 1] = rsB;
        }
        __syncthreads();

        // finish row sums for this sub-chunk: thread t -> (row, 8-lane seg)
        {
            const int row = tid >> 3;       // 0..31 (local)
            const int seg = tid & 7;
            float t = 0.f;
#pragma unroll
            for (int i = 0; i < 8; ++i) t += rpart[seg * 8 + i][row];
            t += __shfl_xor(t, 1, 64);
            t += __shfl_xor(t, 2, 64);
            t += __shfl_xor(t, 4, 64);
            if (seg == 0)
                qout[(size_t)(NREL + r) * NENT + cOut * 128 + i0 + row] =
                    1.f - __expf(-t);
        }
        __syncthreads();   // rpart reads done before next sub-chunk rewrites
    }

    // block epilogue: combine the 4 waves' column partials (overlay rpart)
#pragma unroll
    for (int k = 0; k < 8; ++k)
        *reinterpret_cast<f4*>(&smem[wave][k * 256 + lane * 4]) = acc[k];
    __syncthreads();

    f4* part4 = reinterpret_cast<f4*>(partial) + (size_t)bx * rowStride;
    for (int g = tid; g < NENT / 4; g += 256) {
        f4 a0 = *reinterpret_cast<const f4*>(&smem[0][g * 4]);
        f4 a1 = *reinterpret_cast<const f4*>(&smem[1][g * 4]);
        f4 a2 = *reinterpret_cast<const f4*>(&smem[2][g * 4]);
        f4 a3 = *reinterpret_cast<const f4*>(&smem[3][g * 4]);
        part4[g] = (a0 + a1) + (a2 + a3);
    }
}

// ---------------------------------------------------------------------------
// Kernel B (merged): blocks 0..319 finalize column sums (16 fully-unrolled
// independent chunk loads) + attribute rows; block 320 does the weights
// softmax with fully-unrolled independent loads.
// ---------------------------------------------------------------------------
#define FIN_BLOCKS ((NREL + NATTR) * NENT / 256)   // 320

__global__ __launch_bounds__(256) void finalize_softmax_kernel(
    const float* __restrict__ partial,
    const float* __restrict__ attrs,
    const float* __restrict__ W,
    float* __restrict__ qout,
    float* __restrict__ sw)
{
    const int b = blockIdx.x;
    if (b < FIN_BLOCKS) {
        const int idx = b * 256 + threadIdx.x;   // over (32+8)*2048
        const int row = idx >> 11;
        const int n   = idx & (NENT - 1);
        if (row < NREL) {
            float s = 0.f;
#pragma unroll
            for (int c = 0; c < CHUNKS_OUT; ++c) // 16 independent loads
                s += partial[((size_t)(row * CHUNKS_OUT + c) << 11) + n];
            qout[((size_t)row << 11) + n] = 1.f - __expf(-s);
        } else {
            const int a = row - NREL;
            float v = attrs[((size_t)a << 11) + n];
            qout[((size_t)(2 * NREL + a) << 11) + n] = 1.f - __expf(-2.f * v);
        }
    } else {
        // softmax over the 72 rows of weights, per output column w
        const int w = threadIdx.x;  // 0..255
        float v[NK];
#pragma unroll
        for (int k = 0; k < NK; ++k) v[k] = W[k * WIDTH + w];  // 72 indep loads
        float m = v[0];
#pragma unroll
        for (int k = 1; k < NK; ++k) m = fmaxf(m, v[k]);
        float s = 0.f;
#pragma unroll
        for (int k = 0; k < NK; ++k) { v[k] = __expf(v[k] - m); s += v[k]; }
        const float inv = 1.f / s;
#pragma unroll
        for (int k = 0; k < NK; ++k) sw[k * WIDTH + w] = v[k] * inv;
    }
}

// ---------------------------------------------------------------------------
// Kernel C: outputs[w][n] = sum_k sw[k][w] * quantified[k][n], tiled.
// Block = (32 w's) x (128 cols): quant tile [72][128] (36KB) + sw tile
// [72][32] (9KB) staged in LDS ONCE. 128 blocks.
// ---------------------------------------------------------------------------
#define CW   32
#define CCOL 128

__global__ __launch_bounds__(256) void matmul_kernel(
    const float* __restrict__ sw,
    const float* __restrict__ quant,
    float* __restrict__ out)
{
    __shared__ float qt[NK][CCOL];    // 36KB
    __shared__ float swt[NK][CW];     // 9KB
    const int wg  = blockIdx.x >> 4;       // 0..7
    const int cg  = blockIdx.x & 15;       // 0..15
    const int w0  = wg * CW;
    const int c0  = cg * CCOL;
    const int tid = threadIdx.x;

    const f4* q4 = reinterpret_cast<const f4*>(quant);
#pragma unroll
    for (int i = tid; i < NK * (CCOL / 4); i += 256) {   // 9 iters
        const int k = i >> 5;        // CCOL/4 = 32 float4 per row
        const int c = i & 31;
        *reinterpret_cast<f4*>(&qt[k][c * 4]) =
            q4[(size_t)k * (NENT / 4) + (c0 >> 2) + c];
    }
#pragma unroll
    for (int i = tid; i < NK * CW; i += 256) {           // 9 iters
        const int k  = i >> 5;       // CW = 32
        const int wl = i & 31;
        swt[k][wl] = sw[k * WIDTH + w0 + wl];
    }
    __syncthreads();

    const int wl = tid >> 3;          // 0..31
    const int cl = (tid & 7) * 16;    // col offset, 16 cols/thread
    f4 a0 = (f4)0.f, a1 = (f4)0.f, a2 = (f4)0.f, a3 = (f4)0.f;
#pragma unroll 8
    for (int k = 0; k < NK; ++k) {
        const float s = swt[k][wl];
        const f4* row = reinterpret_cast<const f4*>(&qt[k][cl]);
        f4 v0 = row[0], v1 = row[1], v2 = row[2], v3 = row[3];
        a0 += s * v0; a1 += s * v1; a2 += s * v2; a3 += s * v3;
    }
    f4* o4 = reinterpret_cast<f4*>(out + (size_t)(w0 + wl) * NENT + c0 + cl);
    o4[0] = a0; o4[1] = a1; o4[2] = a2; o4[3] = a3;
}

extern "C" void kernel_launch(void* const* d_in, const int* in_sizes, int n_in,
                              void* d_out, int out_size, void* d_ws, size_t ws_size,
                              hipStream_t stream)
{
    const float* db    = (const float*)d_in[0];  // [32][2048][2048]
    const float* attrs = (const float*)d_in[1];  // [8][2048]
    const float* W     = (const float*)d_in[2];  // [72][256]

    float* out   = (float*)d_out;                    // [256][2048]
    float* quant = out + (size_t)WIDTH * NENT;       // [72][2048]

    float* partial = (float*)d_ws;                               // [512][2048]
    float* sw      = partial + (size_t)NREL * CHUNKS_OUT * NENT; // [72][256]

    reduce_db_kernel<<<NREL * CHUNKS_OUT, 256, 0, stream>>>(
        db, quant, partial, 8, SUBS);
    finalize_softmax_kernel<<<FIN_BLOCKS + 1, 256, 0, stream>>>(
        partial, attrs, W, quant, sw);
    matmul_kernel<<<(WIDTH / CW) * (NENT / CCOL), 256, 0, stream>>>(
        sw, quant, out);
}